// Round 3
// baseline (15.837 us; speedup 1.0000x reference)
//
#include <hip/hip_runtime.h>
#include <hip/hip_bf16.h>

// Problem: N=32, T=5, V=64, F=512, t_mid = 2
// xm = x[:, 2, :, :]                         (32, 64, 512)
// tmpS[n,i,j] = exp( sum_f |xm[n,i,f]-xm[n,j,f]| * a[f] )   (symmetric in i,j)
// colsum[n,i] = sum_k tmpS[n,k,i] == sum_k tmpS[n,i,k]  (symmetry -> row-local)
// S[n,i,j] = tmpS[n,i,j] / colsum[n,i]
//
// R3: register-tile BOTH i (IB=4, from LDS) and j (JB=2, from L2).
// Thread (jg, part): part in 0..7 f-partitions, jg in 0..31, owns j = jg and
// jg+32. Per float4 f-chunk: 5 LDS reads (4 xi + va) feed 32 FMAs -> LDS-pipe
// time halves vs R2. fabs folds into FMA input modifier (2 VALU/elem).

#define NN 32
#define TT 5
#define VV 64
#define FF 512
#define TMID 2
#define IB 4            // i-rows per block
#define RSTRIDE 65      // padded stride for red[] to dodge bank conflicts

__global__ __launch_bounds__(256) void pairsim_kernel(
    const float* __restrict__ x, const float* __restrict__ a,
    float* __restrict__ out) {
  const int b = blockIdx.x;        // 0 .. NN*(VV/IB)-1 = 511
  const int n = b >> 4;
  const int i0 = (b & 15) * IB;
  const int t = threadIdx.x;       // 0 .. 255

  __shared__ float xi[IB * FF];        // 8 KB: rows i0..i0+3
  __shared__ float av[FF];             // 2 KB: weight vector
  __shared__ float red[IB * RSTRIDE];  // exp values, padded rows

  const float* xm = x + ((size_t)n * TT + TMID) * (size_t)VV * FF;

  // Stage xi rows (contiguous 8 KB) + a, float4-coalesced.
  {
    const float4* src_xi = reinterpret_cast<const float4*>(xm + (size_t)i0 * FF);
    const float4* src_a  = reinterpret_cast<const float4*>(a);
    float4* dst_xi = reinterpret_cast<float4*>(xi);
    float4* dst_a  = reinterpret_cast<float4*>(av);
    for (int idx = t; idx < (IB * FF / 4) + (FF / 4); idx += 256) {
      if (idx < IB * FF / 4) dst_xi[idx] = src_xi[idx];
      else                   dst_a[idx - IB * FF / 4] = src_a[idx - IB * FF / 4];
    }
  }
  __syncthreads();

  const int part = t & 7;          // f-partition 0..7
  const int jg   = t >> 3;         // 0..31 -> owns j = jg and jg+32
  const float* xj0 = xm + (size_t)jg * FF;
  const float* xj1 = xm + (size_t)(jg + 32) * FF;

  float a00 = 0.f, a01 = 0.f, a10 = 0.f, a11 = 0.f;
  float a20 = 0.f, a21 = 0.f, a30 = 0.f, a31 = 0.f;

#pragma unroll 4
  for (int k = 0; k < 16; ++k) {
    const int f = k * 32 + part * 4;   // 8-lane part-group covers 128B contig
    float4 vj0 = *reinterpret_cast<const float4*>(xj0 + f);
    float4 vj1 = *reinterpret_cast<const float4*>(xj1 + f);
    float4 va  = *reinterpret_cast<const float4*>(av + f);
    float4 v0  = *reinterpret_cast<const float4*>(xi + 0 * FF + f);
    float4 v1  = *reinterpret_cast<const float4*>(xi + 1 * FF + f);
    float4 v2  = *reinterpret_cast<const float4*>(xi + 2 * FF + f);
    float4 v3  = *reinterpret_cast<const float4*>(xi + 3 * FF + f);

    a00 = fmaf(fabsf(v0.x - vj0.x), va.x, a00);
    a00 = fmaf(fabsf(v0.y - vj0.y), va.y, a00);
    a00 = fmaf(fabsf(v0.z - vj0.z), va.z, a00);
    a00 = fmaf(fabsf(v0.w - vj0.w), va.w, a00);
    a01 = fmaf(fabsf(v0.x - vj1.x), va.x, a01);
    a01 = fmaf(fabsf(v0.y - vj1.y), va.y, a01);
    a01 = fmaf(fabsf(v0.z - vj1.z), va.z, a01);
    a01 = fmaf(fabsf(v0.w - vj1.w), va.w, a01);

    a10 = fmaf(fabsf(v1.x - vj0.x), va.x, a10);
    a10 = fmaf(fabsf(v1.y - vj0.y), va.y, a10);
    a10 = fmaf(fabsf(v1.z - vj0.z), va.z, a10);
    a10 = fmaf(fabsf(v1.w - vj0.w), va.w, a10);
    a11 = fmaf(fabsf(v1.x - vj1.x), va.x, a11);
    a11 = fmaf(fabsf(v1.y - vj1.y), va.y, a11);
    a11 = fmaf(fabsf(v1.z - vj1.z), va.z, a11);
    a11 = fmaf(fabsf(v1.w - vj1.w), va.w, a11);

    a20 = fmaf(fabsf(v2.x - vj0.x), va.x, a20);
    a20 = fmaf(fabsf(v2.y - vj0.y), va.y, a20);
    a20 = fmaf(fabsf(v2.z - vj0.z), va.z, a20);
    a20 = fmaf(fabsf(v2.w - vj0.w), va.w, a20);
    a21 = fmaf(fabsf(v2.x - vj1.x), va.x, a21);
    a21 = fmaf(fabsf(v2.y - vj1.y), va.y, a21);
    a21 = fmaf(fabsf(v2.z - vj1.z), va.z, a21);
    a21 = fmaf(fabsf(v2.w - vj1.w), va.w, a21);

    a30 = fmaf(fabsf(v3.x - vj0.x), va.x, a30);
    a30 = fmaf(fabsf(v3.y - vj0.y), va.y, a30);
    a30 = fmaf(fabsf(v3.z - vj0.z), va.z, a30);
    a30 = fmaf(fabsf(v3.w - vj0.w), va.w, a30);
    a31 = fmaf(fabsf(v3.x - vj1.x), va.x, a31);
    a31 = fmaf(fabsf(v3.y - vj1.y), va.y, a31);
    a31 = fmaf(fabsf(v3.z - vj1.z), va.z, a31);
    a31 = fmaf(fabsf(v3.w - vj1.w), va.w, a31);
  }

  // Fold the 8 f-partitions (xor butterfly within each 8-lane part-group;
  // leaves the full sum in every lane of the group).
  a00 += __shfl_xor(a00, 1); a00 += __shfl_xor(a00, 2); a00 += __shfl_xor(a00, 4);
  a01 += __shfl_xor(a01, 1); a01 += __shfl_xor(a01, 2); a01 += __shfl_xor(a01, 4);
  a10 += __shfl_xor(a10, 1); a10 += __shfl_xor(a10, 2); a10 += __shfl_xor(a10, 4);
  a11 += __shfl_xor(a11, 1); a11 += __shfl_xor(a11, 2); a11 += __shfl_xor(a11, 4);
  a20 += __shfl_xor(a20, 1); a20 += __shfl_xor(a20, 2); a20 += __shfl_xor(a20, 4);
  a21 += __shfl_xor(a21, 1); a21 += __shfl_xor(a21, 2); a21 += __shfl_xor(a21, 4);
  a30 += __shfl_xor(a30, 1); a30 += __shfl_xor(a30, 2); a30 += __shfl_xor(a30, 4);
  a31 += __shfl_xor(a31, 1); a31 += __shfl_xor(a31, 2); a31 += __shfl_xor(a31, 4);

  // Distribute exp: each thread writes exactly one exp value.
  // part selects (row r = part&3, j-half = part>>2).
  {
    const int r  = part & 3;
    const bool hi = part >= 4;
    float pick = 0.f;
    pick = (r == 0) ? (hi ? a01 : a00) : pick;
    pick = (r == 1) ? (hi ? a11 : a10) : pick;
    pick = (r == 2) ? (hi ? a21 : a20) : pick;
    pick = (r == 3) ? (hi ? a31 : a30) : pick;
    const int j = hi ? (jg + 32) : jg;
    red[r * RSTRIDE + j] = expf(pick);
  }
  __syncthreads();

  // 4 waves, one per i-row: butterfly row-sum, coalesced 256B row write.
  {
    const int w = t >> 6;          // 0..3 -> i-row
    const int lane = t & 63;       // j
    float v = red[w * RSTRIDE + lane];
    float s = v;
#pragma unroll
    for (int o = 1; o < 64; o <<= 1) s += __shfl_xor(s, o);
    out[(((size_t)n * VV + i0 + w) << 6) + lane] = v / s;
  }
}

extern "C" void kernel_launch(void* const* d_in, const int* in_sizes, int n_in,
                              void* d_out, int out_size, void* d_ws, size_t ws_size,
                              hipStream_t stream) {
  const float* x = (const float*)d_in[0];
  const float* a = (const float*)d_in[1];
  float* out = (float*)d_out;
  pairsim_kernel<<<NN * (VV / IB), 256, 0, stream>>>(x, a, out);
}

// Round 4
// 14.567 us; speedup vs baseline: 1.0872x; 1.0872x over previous
//
#include <hip/hip_runtime.h>
#include <hip/hip_bf16.h>

// Problem: N=32, T=5, V=64, F=512, t_mid = 2
// xm = x[:, 2, :, :]                         (32, 64, 512)
// tmpS[n,i,j] = exp( sum_f |xm[n,i,f]-xm[n,j,f]| * a[f] )   (symmetric in i,j)
// colsum[n,i] = sum_k tmpS[n,k,i] == sum_k tmpS[n,i,k]  (symmetry -> row-local)
// S[n,i,j] = tmpS[n,i,j] / colsum[n,i]
//
// R4: IB=4 (xi from LDS) x JB=4 (xj from L2, register-prefetched).
// 256 threads = 16 f-parts x 16 j-groups; 8 k-iterations, no unroll.
// Per iter: 5 LDS b128 + 4 global b128 feed 64 FMAs.

#define NN 32
#define TT 5
#define VV 64
#define FF 512
#define TMID 2
#define IB 4            // i-rows per block (LDS-staged)
#define RSTRIDE 65      // padded stride for red[]

__global__ __launch_bounds__(256) void pairsim_kernel(
    const float* __restrict__ x, const float* __restrict__ a,
    float* __restrict__ out) {
  const int b = blockIdx.x;        // 0 .. NN*(VV/IB)-1 = 511
  const int n = b >> 4;
  const int i0 = (b & 15) * IB;
  const int t = threadIdx.x;       // 0 .. 255

  __shared__ float xi[IB * FF];        // 8 KB
  __shared__ float av[FF];             // 2 KB
  __shared__ float red[IB * RSTRIDE];  // ~1 KB

  const float* xm = x + ((size_t)n * TT + TMID) * (size_t)VV * FF;

  // Stage xi rows (contiguous 8 KB) + a, float4-coalesced.
  {
    const float4* src_xi = reinterpret_cast<const float4*>(xm + (size_t)i0 * FF);
    const float4* src_a  = reinterpret_cast<const float4*>(a);
    float4* dst_xi = reinterpret_cast<float4*>(xi);
    float4* dst_a  = reinterpret_cast<float4*>(av);
    for (int idx = t; idx < (IB * FF / 4) + (FF / 4); idx += 256) {
      if (idx < IB * FF / 4) dst_xi[idx] = src_xi[idx];
      else                   dst_a[idx - IB * FF / 4] = src_a[idx - IB * FF / 4];
    }
  }

  const int part = t & 15;         // f-partition 0..15
  const int jg   = t >> 4;         // 0..15; owns j = jg + 16*jsel
  const float* xj0 = xm + (size_t)(jg     ) * FF;
  const float* xj1 = xm + (size_t)(jg + 16) * FF;
  const float* xj2 = xm + (size_t)(jg + 32) * FF;
  const float* xj3 = xm + (size_t)(jg + 48) * FF;

  float acc[4][4];                 // [i][jsel] — all indices compile-time
#pragma unroll
  for (int i = 0; i < 4; ++i)
#pragma unroll
    for (int js = 0; js < 4; ++js) acc[i][js] = 0.f;

  // Prefetch k=0 j-tiles (issued before __syncthreads so they overlap staging).
  int f = part * 4;                // k*64 + part*4, k=0
  float4 vj0 = *reinterpret_cast<const float4*>(xj0 + f);
  float4 vj1 = *reinterpret_cast<const float4*>(xj1 + f);
  float4 vj2 = *reinterpret_cast<const float4*>(xj2 + f);
  float4 vj3 = *reinterpret_cast<const float4*>(xj3 + f);

  __syncthreads();

#pragma unroll 1
  for (int k = 0; k < 8; ++k) {
    const int fn = (k + 1) * 64 + part * 4;
    float4 nj0, nj1, nj2, nj3;
    if (k < 7) {                   // prefetch next j-tiles
      nj0 = *reinterpret_cast<const float4*>(xj0 + fn);
      nj1 = *reinterpret_cast<const float4*>(xj1 + fn);
      nj2 = *reinterpret_cast<const float4*>(xj2 + fn);
      nj3 = *reinterpret_cast<const float4*>(xj3 + fn);
    }
    const int fc = k * 64 + part * 4;
    float4 va = *reinterpret_cast<const float4*>(av + fc);
    float4 vi[4];
    vi[0] = *reinterpret_cast<const float4*>(xi + 0 * FF + fc);
    vi[1] = *reinterpret_cast<const float4*>(xi + 1 * FF + fc);
    vi[2] = *reinterpret_cast<const float4*>(xi + 2 * FF + fc);
    vi[3] = *reinterpret_cast<const float4*>(xi + 3 * FF + fc);

#pragma unroll
    for (int i = 0; i < 4; ++i) {
      acc[i][0] = fmaf(fabsf(vi[i].x - vj0.x), va.x, acc[i][0]);
      acc[i][0] = fmaf(fabsf(vi[i].y - vj0.y), va.y, acc[i][0]);
      acc[i][0] = fmaf(fabsf(vi[i].z - vj0.z), va.z, acc[i][0]);
      acc[i][0] = fmaf(fabsf(vi[i].w - vj0.w), va.w, acc[i][0]);
      acc[i][1] = fmaf(fabsf(vi[i].x - vj1.x), va.x, acc[i][1]);
      acc[i][1] = fmaf(fabsf(vi[i].y - vj1.y), va.y, acc[i][1]);
      acc[i][1] = fmaf(fabsf(vi[i].z - vj1.z), va.z, acc[i][1]);
      acc[i][1] = fmaf(fabsf(vi[i].w - vj1.w), va.w, acc[i][1]);
      acc[i][2] = fmaf(fabsf(vi[i].x - vj2.x), va.x, acc[i][2]);
      acc[i][2] = fmaf(fabsf(vi[i].y - vj2.y), va.y, acc[i][2]);
      acc[i][2] = fmaf(fabsf(vi[i].z - vj2.z), va.z, acc[i][2]);
      acc[i][2] = fmaf(fabsf(vi[i].w - vj2.w), va.w, acc[i][2]);
      acc[i][3] = fmaf(fabsf(vi[i].x - vj3.x), va.x, acc[i][3]);
      acc[i][3] = fmaf(fabsf(vi[i].y - vj3.y), va.y, acc[i][3]);
      acc[i][3] = fmaf(fabsf(vi[i].z - vj3.z), va.z, acc[i][3]);
      acc[i][3] = fmaf(fabsf(vi[i].w - vj3.w), va.w, acc[i][3]);
    }
    vj0 = nj0; vj1 = nj1; vj2 = nj2; vj3 = nj3;
  }

  // Fold the 16 f-partitions within each 16-lane group.
#pragma unroll
  for (int i = 0; i < 4; ++i)
#pragma unroll
    for (int js = 0; js < 4; ++js) {
      float v = acc[i][js];
      v += __shfl_xor(v, 1);
      v += __shfl_xor(v, 2);
      v += __shfl_xor(v, 4);
      v += __shfl_xor(v, 8);
      acc[i][js] = v;
    }

  // Each thread writes exactly one exp value: part -> (ri = part&3, rj = part>>2).
  {
    const int ri = part & 3;
    const int rj = part >> 2;
    float pick = 0.f;
#pragma unroll
    for (int i = 0; i < 4; ++i)
#pragma unroll
      for (int js = 0; js < 4; ++js)
        if (ri == i && rj == js) pick = acc[i][js];
    red[ri * RSTRIDE + jg + (rj << 4)] = expf(pick);
  }
  __syncthreads();

  // 4 waves, one per i-row: butterfly row-sum, coalesced 256B row write.
  {
    const int w = t >> 6;          // i-row
    const int lane = t & 63;       // j
    float v = red[w * RSTRIDE + lane];
    float s = v;
#pragma unroll
    for (int o = 1; o < 64; o <<= 1) s += __shfl_xor(s, o);
    out[(((size_t)n * VV + i0 + w) << 6) + lane] = v / s;
  }
}

extern "C" void kernel_launch(void* const* d_in, const int* in_sizes, int n_in,
                              void* d_out, int out_size, void* d_ws, size_t ws_size,
                              hipStream_t stream) {
  const float* x = (const float*)d_in[0];
  const float* a = (const float*)d_in[1];
  float* out = (float*)d_out;
  pairsim_kernel<<<NN * (VV / IB), 256, 0, stream>>>(x, a, out);
}

// Round 5
// 14.019 us; speedup vs baseline: 1.1297x; 1.0391x over previous
//
#include <hip/hip_runtime.h>
#include <hip/hip_bf16.h>

// Problem: N=32, T=5, V=64, F=512, t_mid = 2
// xm = x[:, 2, :, :]                         (32, 64, 512)
// tmpS[n,i,j] = exp( sum_f |xm[n,i,f]-xm[n,j,f]| * a[f] )   (symmetric in i,j)
// colsum[n,i] = sum_k tmpS[n,k,i] == sum_k tmpS[n,i,k]  (symmetry -> row-local)
// S[n,i,j] = tmpS[n,i,j] / colsum[n,i]
//
// R5: R4's tiling (IB=4 x JB=4, 16 f-parts, 8 k-iters) + R2's loop
// discipline (FULL unroll, no manual prefetch, no branches in body).
// Per iter: 5 LDS b128 + 4 global b128 feed 64 FMAs.

#define NN 32
#define TT 5
#define VV 64
#define FF 512
#define TMID 2
#define IB 4            // i-rows per block (LDS-staged)
#define RSTRIDE 65      // padded stride for red[]

__global__ __launch_bounds__(256) void pairsim_kernel(
    const float* __restrict__ x, const float* __restrict__ a,
    float* __restrict__ out) {
  const int b = blockIdx.x;        // 0 .. NN*(VV/IB)-1 = 511
  const int n = b >> 4;
  const int i0 = (b & 15) * IB;
  const int t = threadIdx.x;       // 0 .. 255

  __shared__ float xi[IB * FF];        // 8 KB
  __shared__ float av[FF];             // 2 KB
  __shared__ float red[IB * RSTRIDE];  // ~1 KB

  const float* xm = x + ((size_t)n * TT + TMID) * (size_t)VV * FF;

  // Stage xi rows (contiguous 8 KB) + a, float4-coalesced.
  {
    const float4* src_xi = reinterpret_cast<const float4*>(xm + (size_t)i0 * FF);
    const float4* src_a  = reinterpret_cast<const float4*>(a);
    float4* dst_xi = reinterpret_cast<float4*>(xi);
    float4* dst_a  = reinterpret_cast<float4*>(av);
    for (int idx = t; idx < (IB * FF / 4) + (FF / 4); idx += 256) {
      if (idx < IB * FF / 4) dst_xi[idx] = src_xi[idx];
      else                   dst_a[idx - IB * FF / 4] = src_a[idx - IB * FF / 4];
    }
  }
  __syncthreads();

  const int part = t & 15;         // f-partition 0..15
  const int jg   = t >> 4;         // 0..15; owns j = jg + 16*js
  const float* xj0 = xm + (size_t)(jg     ) * FF;
  const float* xj1 = xm + (size_t)(jg + 16) * FF;
  const float* xj2 = xm + (size_t)(jg + 32) * FF;
  const float* xj3 = xm + (size_t)(jg + 48) * FF;

  float acc[4][4];                 // [i][js] — all indices compile-time
#pragma unroll
  for (int i = 0; i < 4; ++i)
#pragma unroll
    for (int js = 0; js < 4; ++js) acc[i][js] = 0.f;

#pragma unroll
  for (int k = 0; k < 8; ++k) {
    const int f = k * 64 + part * 4;   // 16-lane part-group covers 256B contig
    float4 vj0 = *reinterpret_cast<const float4*>(xj0 + f);
    float4 vj1 = *reinterpret_cast<const float4*>(xj1 + f);
    float4 vj2 = *reinterpret_cast<const float4*>(xj2 + f);
    float4 vj3 = *reinterpret_cast<const float4*>(xj3 + f);
    float4 va  = *reinterpret_cast<const float4*>(av + f);
    float4 v0  = *reinterpret_cast<const float4*>(xi + 0 * FF + f);
    float4 v1  = *reinterpret_cast<const float4*>(xi + 1 * FF + f);
    float4 v2  = *reinterpret_cast<const float4*>(xi + 2 * FF + f);
    float4 v3  = *reinterpret_cast<const float4*>(xi + 3 * FF + f);

#define MACS(ACCROW, VI)                                   \
    ACCROW[0] = fmaf(fabsf(VI.x - vj0.x), va.x, ACCROW[0]); \
    ACCROW[0] = fmaf(fabsf(VI.y - vj0.y), va.y, ACCROW[0]); \
    ACCROW[0] = fmaf(fabsf(VI.z - vj0.z), va.z, ACCROW[0]); \
    ACCROW[0] = fmaf(fabsf(VI.w - vj0.w), va.w, ACCROW[0]); \
    ACCROW[1] = fmaf(fabsf(VI.x - vj1.x), va.x, ACCROW[1]); \
    ACCROW[1] = fmaf(fabsf(VI.y - vj1.y), va.y, ACCROW[1]); \
    ACCROW[1] = fmaf(fabsf(VI.z - vj1.z), va.z, ACCROW[1]); \
    ACCROW[1] = fmaf(fabsf(VI.w - vj1.w), va.w, ACCROW[1]); \
    ACCROW[2] = fmaf(fabsf(VI.x - vj2.x), va.x, ACCROW[2]); \
    ACCROW[2] = fmaf(fabsf(VI.y - vj2.y), va.y, ACCROW[2]); \
    ACCROW[2] = fmaf(fabsf(VI.z - vj2.z), va.z, ACCROW[2]); \
    ACCROW[2] = fmaf(fabsf(VI.w - vj2.w), va.w, ACCROW[2]); \
    ACCROW[3] = fmaf(fabsf(VI.x - vj3.x), va.x, ACCROW[3]); \
    ACCROW[3] = fmaf(fabsf(VI.y - vj3.y), va.y, ACCROW[3]); \
    ACCROW[3] = fmaf(fabsf(VI.z - vj3.z), va.z, ACCROW[3]); \
    ACCROW[3] = fmaf(fabsf(VI.w - vj3.w), va.w, ACCROW[3]);

    MACS(acc[0], v0)
    MACS(acc[1], v1)
    MACS(acc[2], v2)
    MACS(acc[3], v3)
#undef MACS
  }

  // Fold the 16 f-partitions within each 16-lane group.
#pragma unroll
  for (int i = 0; i < 4; ++i)
#pragma unroll
    for (int js = 0; js < 4; ++js) {
      float v = acc[i][js];
      v += __shfl_xor(v, 1);
      v += __shfl_xor(v, 2);
      v += __shfl_xor(v, 4);
      v += __shfl_xor(v, 8);
      acc[i][js] = v;
    }

  // Each thread writes exactly one exp value: part -> (ri = part&3, rj = part>>2).
  {
    const int ri = part & 3;
    const int rj = part >> 2;
    float pick = 0.f;
#pragma unroll
    for (int i = 0; i < 4; ++i)
#pragma unroll
      for (int js = 0; js < 4; ++js)
        if (ri == i && rj == js) pick = acc[i][js];
    red[ri * RSTRIDE + jg + (rj << 4)] = __expf(pick);
  }
  __syncthreads();

  // 4 waves, one per i-row: butterfly row-sum, coalesced 256B row write.
  {
    const int w = t >> 6;          // i-row
    const int lane = t & 63;       // j
    float v = red[w * RSTRIDE + lane];
    float s = v;
#pragma unroll
    for (int o = 1; o < 64; o <<= 1) s += __shfl_xor(s, o);
    out[(((size_t)n * VV + i0 + w) << 6) + lane] = v / s;
  }
}

extern "C" void kernel_launch(void* const* d_in, const int* in_sizes, int n_in,
                              void* d_out, int out_size, void* d_ws, size_t ws_size,
                              hipStream_t stream) {
  const float* x = (const float*)d_in[0];
  const float* a = (const float*)d_in[1];
  float* out = (float*)d_out;
  pairsim_kernel<<<NN * (VV / IB), 256, 0, stream>>>(x, a, out);
}